// Round 8
// baseline (135451.880 us; speedup 1.0000x reference)
//
#include <hip/hip_runtime.h>
#include <hip/hip_bf16.h>
#include <math.h>

// Problem dims (fixed by the reference)
namespace {
constexpr int B  = 512;
constexpr int S  = 1024;
constexpr int ID = 64;    // input / output feature dim
constexpr int H  = 512;
constexpr int T  = 256;
constexpr int NKT = 18;   // K-chunks of 32: 16 over h (K=512) + 2 over x/y (K=64)
constexpr int ROWS = 16;  // batch rows per block
constexpr int NBLK = B / ROWS;   // 32 blocks, fully independent
constexpr int HP = 520;   // padded h row (ushort): stride 1040B -> conflict-free b128
constexpr int YP = 72;    // padded y row (ushort): stride 144B, 16B-aligned
}

using short8  = __attribute__((ext_vector_type(8))) short;
using float4v = __attribute__((ext_vector_type(4))) float;

// ---- helpers ----------------------------------------------------------------
__device__ inline ushort bfbits(float x) {
    union { __hip_bfloat16 h; ushort u; } cv;
    cv.h = __float2bfloat16(x);   // RNE
    return cv.u;
}
__device__ inline short8 pack8(float4v f0, float4v f1) {
    short8 a;
    a[0]=(short)bfbits(f0[0]); a[1]=(short)bfbits(f0[1]);
    a[2]=(short)bfbits(f0[2]); a[3]=(short)bfbits(f0[3]);
    a[4]=(short)bfbits(f1[0]); a[5]=(short)bfbits(f1[1]);
    a[6]=(short)bfbits(f1[2]); a[7]=(short)bfbits(f1[3]);
    return a;
}
__device__ __forceinline__ float sigm_f(float x)  { return 1.f / (1.f + __expf(-x)); }
__device__ __forceinline__ float tanh_ff(float x) { const float e = __expf(2.f * x);
                                                    return 1.f - 2.f / (e + 1.f); }

// ---- one-time prep ----------------------------------------------------------
// Swizzle [Wh | Wi] (fp32) into MFMA-native bf16 B-fragments.
// Frag (g, jt, kt): lane l elem i = W[g*512 + jt*16 + (l&15)][kt*32 + (l>>4)*8 + i]
__global__ __launch_bounds__(256) void prep_swizzle(const float* __restrict__ Wh,
                                                    const float* __restrict__ Wi,
                                                    ushort* __restrict__ Bs) {
    const int t = blockIdx.x * 256 + threadIdx.x;
    constexpr int TOT = 3 * 32 * NKT * 64;
    if (t >= TOT) return;
    const int l   = t & 63;
    int rest      = t >> 6;
    const int kt  = rest % NKT;  rest /= NKT;
    const int jt  = rest & 31;
    const int g   = rest >> 5;
    const int j  = jt * 16 + (l & 15);
    const int kb = kt * 32 + ((l >> 4) << 3);
    ushort v[8];
    if (kt < 16) {
        const float* src = Wh + (long)(g * H + j) * H + kb;
        #pragma unroll
        for (int i = 0; i < 8; ++i) v[i] = bfbits(src[i]);
    } else {
        const float* src = Wi + (long)(g * H + j) * ID + (kb - H);
        #pragma unroll
        for (int i = 0; i < 8; ++i) v[i] = bfbits(src[i]);
    }
    *(short8*)(Bs + (size_t)t * 8) = *(short8*)v;
}

// Swizzle Wl [ID,H] into bf16 B-fragments: frag (ct,kt).
__global__ __launch_bounds__(256) void prep_wl(const float* __restrict__ Wl,
                                               ushort* __restrict__ Wsl) {
    const int t = blockIdx.x * 256 + threadIdx.x;
    if (t >= 4 * 16 * 64) return;
    const int l  = t & 63;
    const int kt = (t >> 6) & 15;
    const int ct = t >> 10;
    const int jy = ct * 16 + (l & 15);
    const int kc = kt * 32 + ((l >> 4) << 3);
    ushort v[8];
    #pragma unroll
    for (int i = 0; i < 8; ++i) v[i] = bfbits(Wl[(long)jy * H + kc + i]);
    *(short8*)(Wsl + (size_t)t * 8) = *(short8*)v;
}

// ---- THE kernel: block-private recurrence, zero inter-block communication ---
// 32 blocks x 256 thr. Block bk owns batch rows [bk*16, bk*16+16) and computes
// the full 512-wide hidden state for them across all 1280 steps.
// Wave w owns hidden j-tiles jt = w*8 .. w*8+7 (all 3 gates) + y ct-tile w.
__global__ __launch_bounds__(256, 1) void gru_private(
    const float* __restrict__ x,     // [B, S, ID] fp32
    const ushort* __restrict__ Bs,   // swizzled [Wh|Wi], 1.73 MB (L2-resident)
    const ushort* __restrict__ Wsl,  // swizzled Wl, 64 KB
    const float* __restrict__ bi, const float* __restrict__ bh,
    const float* __restrict__ bl,
    float* __restrict__ out)         // [B, T, ID] fp32
{
    __shared__ ushort hsm[2][ROWS][HP];  // 33.3 KB bf16 h ping-pong
    __shared__ ushort ysm[2][ROWS][YP];  // 4.6 KB bf16 y ping-pong

    const int tid = threadIdx.x, w = tid >> 6, l = tid & 63;
    const int r16 = l & 15, kq = l >> 4;
    const int bk  = blockIdx.x;
    const int jt0 = w * 8;

    // zero h buffer 0 (= h0)
    {
        ushort* hz = &hsm[0][0][0];
        for (int i = tid; i < ROWS * HP; i += 256) hz[i] = 0;
    }
    __syncthreads();

    // per-tile biases
    float bir[8], biz[8], binv[8], bhnv[8];
    #pragma unroll
    for (int u = 0; u < 8; ++u) {
        const int j = (jt0 + u) * 16 + r16;
        bir[u]  = bi[j] + bh[j];
        biz[u]  = bi[H + j] + bh[H + j];
        binv[u] = bi[2 * H + j];
        bhnv[u] = bh[2 * H + j];
    }
    const float blw = bl[w * 16 + r16];

    constexpr size_t GS = (size_t)32 * NKT * 512;  // ushorts per gate in Bs
    const ushort* bsl = Bs + (size_t)l * 8;

    float hprev[8][4];
    #pragma unroll
    for (int u = 0; u < 8; ++u)
        #pragma unroll
        for (int c = 0; c < 4; ++c) hprev[u][c] = 0.f;

    const float* xrow = x + (size_t)(bk * ROWS + r16) * S * ID;
    const int c0 = kq * 8;
    float4v xa = *(const float4v*)(xrow + c0);
    float4v xb = *(const float4v*)(xrow + c0 + 4);
    float4v xc = *(const float4v*)(xrow + 32 + c0);
    float4v xd = *(const float4v*)(xrow + 36 + c0);

    // ===================== encoder =====================
    for (int t = 0; t < S; ++t) {
        const int p = t & 1;
        short8 afr[18];
        #pragma unroll
        for (int kt = 0; kt < 16; ++kt)
            afr[kt] = *(const short8*)&hsm[p][r16][kt * 32 + c0];
        afr[16] = pack8(xa, xb);
        afr[17] = pack8(xc, xd);
        if (t + 1 < S) {  // prefetch next x under the MFMA loop
            const float* xr = xrow + (size_t)(t + 1) * ID;
            xa = *(const float4v*)(xr + c0);      xb = *(const float4v*)(xr + c0 + 4);
            xc = *(const float4v*)(xr + 32 + c0); xd = *(const float4v*)(xr + 36 + c0);
        }
        float4v aR[8], aZ[8], aNH[8], aNX[8];
        #pragma unroll
        for (int u = 0; u < 8; ++u) {
            aR[u] = float4v{0.f,0.f,0.f,0.f};  aZ[u] = float4v{0.f,0.f,0.f,0.f};
            aNH[u] = float4v{0.f,0.f,0.f,0.f}; aNX[u] = float4v{0.f,0.f,0.f,0.f};
        }
        #pragma unroll
        for (int kt = 0; kt < 18; ++kt) {
            short8 bfr[24];
            #pragma unroll
            for (int u = 0; u < 8; ++u) {
                const size_t base = (size_t)((jt0 + u) * NKT + kt) * 512;
                bfr[u * 3 + 0] = *(const short8*)(bsl + base);
                bfr[u * 3 + 1] = *(const short8*)(bsl + base + GS);
                bfr[u * 3 + 2] = *(const short8*)(bsl + base + 2 * GS);
            }
            #pragma unroll
            for (int u = 0; u < 8; ++u) {
                aR[u] = __builtin_amdgcn_mfma_f32_16x16x32_bf16(afr[kt], bfr[u*3+0], aR[u], 0, 0, 0);
                aZ[u] = __builtin_amdgcn_mfma_f32_16x16x32_bf16(afr[kt], bfr[u*3+1], aZ[u], 0, 0, 0);
                if (kt < 16)
                    aNH[u] = __builtin_amdgcn_mfma_f32_16x16x32_bf16(afr[kt], bfr[u*3+2], aNH[u], 0, 0, 0);
                else
                    aNX[u] = __builtin_amdgcn_mfma_f32_16x16x32_bf16(afr[kt], bfr[u*3+2], aNX[u], 0, 0, 0);
            }
        }
        #pragma unroll
        for (int u = 0; u < 8; ++u) {
            const int j = (jt0 + u) * 16 + r16;
            #pragma unroll
            for (int c = 0; c < 4; ++c) {
                const float r = sigm_f(aR[u][c] + bir[u]);
                const float z = sigm_f(aZ[u][c] + biz[u]);
                const float n = tanh_ff(aNX[u][c] + binv[u] + r * (aNH[u][c] + bhnv[u]));
                const float hnew = (1.f - z) * n + z * hprev[u][c];
                hprev[u][c] = hnew;
                hsm[p ^ 1][kq * 4 + c][j] = bfbits(hnew);
            }
        }
        __syncthreads();
    }

    // ===================== y0 = h_n @ Wl.T + bl (into ysm[0] only) ============
    {
        short8 ha[16];
        #pragma unroll
        for (int kt = 0; kt < 16; ++kt)
            ha[kt] = *(const short8*)&hsm[0][r16][kt * 32 + c0];
        float4v yac{0.f, 0.f, 0.f, 0.f};
        #pragma unroll
        for (int kt = 0; kt < 16; ++kt) {
            const short8 wb = *(const short8*)(Wsl + (size_t)(w * 16 + kt) * 512 + l * 8);
            yac = __builtin_amdgcn_mfma_f32_16x16x32_bf16(ha[kt], wb, yac, 0, 0, 0);
        }
        #pragma unroll
        for (int c = 0; c < 4; ++c)
            ysm[0][kq * 4 + c][w * 16 + r16] = bfbits(yac[c] + blw);
    }
    __syncthreads();

    // ===================== decoder =====================
    for (int t = 0; t < T; ++t) {
        const int p = t & 1;
        short8 afr[18];
        #pragma unroll
        for (int kt = 0; kt < 16; ++kt)
            afr[kt] = *(const short8*)&hsm[p][r16][kt * 32 + c0];
        afr[16] = *(const short8*)&ysm[p][r16][c0];
        afr[17] = *(const short8*)&ysm[p][r16][32 + c0];

        float4v aR[8], aZ[8], aNH[8], aNX[8];
        #pragma unroll
        for (int u = 0; u < 8; ++u) {
            aR[u] = float4v{0.f,0.f,0.f,0.f};  aZ[u] = float4v{0.f,0.f,0.f,0.f};
            aNH[u] = float4v{0.f,0.f,0.f,0.f}; aNX[u] = float4v{0.f,0.f,0.f,0.f};
        }
        #pragma unroll
        for (int kt = 0; kt < 18; ++kt) {
            short8 bfr[24];
            #pragma unroll
            for (int u = 0; u < 8; ++u) {
                const size_t base = (size_t)((jt0 + u) * NKT + kt) * 512;
                bfr[u * 3 + 0] = *(const short8*)(bsl + base);
                bfr[u * 3 + 1] = *(const short8*)(bsl + base + GS);
                bfr[u * 3 + 2] = *(const short8*)(bsl + base + 2 * GS);
            }
            #pragma unroll
            for (int u = 0; u < 8; ++u) {
                aR[u] = __builtin_amdgcn_mfma_f32_16x16x32_bf16(afr[kt], bfr[u*3+0], aR[u], 0, 0, 0);
                aZ[u] = __builtin_amdgcn_mfma_f32_16x16x32_bf16(afr[kt], bfr[u*3+1], aZ[u], 0, 0, 0);
                if (kt < 16)
                    aNH[u] = __builtin_amdgcn_mfma_f32_16x16x32_bf16(afr[kt], bfr[u*3+2], aNH[u], 0, 0, 0);
                else
                    aNX[u] = __builtin_amdgcn_mfma_f32_16x16x32_bf16(afr[kt], bfr[u*3+2], aNX[u], 0, 0, 0);
            }
        }
        #pragma unroll
        for (int u = 0; u < 8; ++u) {
            const int j = (jt0 + u) * 16 + r16;
            #pragma unroll
            for (int c = 0; c < 4; ++c) {
                const float r = sigm_f(aR[u][c] + bir[u]);
                const float z = sigm_f(aZ[u][c] + biz[u]);
                const float n = tanh_ff(aNX[u][c] + binv[u] + r * (aNH[u][c] + bhnv[u]));
                const float hnew = (1.f - z) * n + z * hprev[u][c];
                hprev[u][c] = hnew;
                hsm[p ^ 1][kq * 4 + c][j] = bfbits(hnew);
            }
        }
        __syncthreads();   // h_{t+1} visible block-wide

        // y_{t+1} = h_{t+1} @ Wl.T + bl  -> ysm[p^1] + out[:, t, :]
        {
            short8 ha[16];
            #pragma unroll
            for (int kt = 0; kt < 16; ++kt)
                ha[kt] = *(const short8*)&hsm[p ^ 1][r16][kt * 32 + c0];
            float4v yac{0.f, 0.f, 0.f, 0.f};
            #pragma unroll
            for (int kt = 0; kt < 16; ++kt) {
                const short8 wb = *(const short8*)(Wsl + (size_t)(w * 16 + kt) * 512 + l * 8);
                yac = __builtin_amdgcn_mfma_f32_16x16x32_bf16(ha[kt], wb, yac, 0, 0, 0);
            }
            #pragma unroll
            for (int c = 0; c < 4; ++c) {
                const float yv = yac[c] + blw;
                ysm[p ^ 1][kq * 4 + c][w * 16 + r16] = bfbits(yv);
                out[(size_t)(bk * ROWS + kq * 4 + c) * T * ID + (size_t)t * ID
                    + w * 16 + r16] = yv;
            }
        }
        __syncthreads();   // y visible before next step reads it
    }
}

extern "C" void kernel_launch(void* const* d_in, const int* in_sizes, int n_in,
                              void* d_out, int out_size, void* d_ws, size_t ws_size,
                              hipStream_t stream) {
    const float* x  = (const float*)d_in[0];   // [B,S,ID]
    const float* Wi = (const float*)d_in[1];   // [3H,ID]
    const float* Wh = (const float*)d_in[2];   // [3H,H]
    const float* bi = (const float*)d_in[3];   // [3H]
    const float* bh = (const float*)d_in[4];   // [3H]
    const float* Wl = (const float*)d_in[5];   // [ID,H]
    const float* bl = (const float*)d_in[6];   // [ID]
    float* out = (float*)d_out;                // [B,T,ID]

    // workspace: swizzled weights only
    ushort* Bs  = (ushort*)d_ws;                          // 1.73 MB
    ushort* Wsl = Bs + (size_t)3 * 32 * NKT * 512;        // 64 KB

    prep_swizzle<<<(3 * 32 * NKT * 64 + 255) / 256, 256, 0, stream>>>(Wh, Wi, Bs);
    prep_wl<<<(4 * 16 * 64 + 255) / 256, 256, 0, stream>>>(Wl, Wsl);

    gru_private<<<NBLK, 256, 0, stream>>>(x, Bs, Wsl, bi, bh, bl, out);
}

// Round 9
// 6016.360 us; speedup vs baseline: 22.5139x; 22.5139x over previous
//
#include <hip/hip_runtime.h>
#include <hip/hip_bf16.h>
#include <math.h>

// Problem dims (fixed by the reference)
namespace {
constexpr int B  = 512;
constexpr int S  = 1024;
constexpr int ID = 64;    // input / output feature dim
constexpr int H  = 512;
constexpr int T  = 256;
constexpr int NKT = 18;   // K-chunks of 32: 16 over h (K=512) + 2 over x/y (K=64)
constexpr int BT = 32;    // btile count (16 rows each)
constexpr int JQ = 8;     // j-quad blocks per btile (64 cols each)
}

using short8  = __attribute__((ext_vector_type(8))) short;
using float4v = __attribute__((ext_vector_type(4))) float;
typedef unsigned long long u64t;

// ---- helpers ----------------------------------------------------------------
__device__ inline ushort bfbits(float x) {
    union { __hip_bfloat16 h; ushort u; } cv;
    cv.h = __float2bfloat16(x);   // RNE
    return cv.u;
}
__device__ inline short8 pack8(float4v f0, float4v f1) {
    short8 a;
    a[0]=(short)bfbits(f0[0]); a[1]=(short)bfbits(f0[1]);
    a[2]=(short)bfbits(f0[2]); a[3]=(short)bfbits(f0[3]);
    a[4]=(short)bfbits(f1[0]); a[5]=(short)bfbits(f1[1]);
    a[6]=(short)bfbits(f1[2]); a[7]=(short)bfbits(f1[3]);
    return a;
}
__device__ inline short8 cvt8(const float* __restrict__ p) {
    return pack8(*(const float4v*)p, *(const float4v*)(p + 4));
}

// ---- one-time prep ----------------------------------------------------------
// Zero bar + hX; prefill out/y0 with bl, hA with 0 (fallback needs them).
__global__ __launch_bounds__(256) void init_kernel(float* __restrict__ out,
                                                   float* __restrict__ y0,
                                                   float* __restrict__ hA,
                                                   ushort* __restrict__ hX,
                                                   uint* __restrict__ bar,
                                                   const float* __restrict__ bl) {
    const long n_out = (long)B * T * ID;
    const long n_y0  = n_out + (long)B * ID;
    const long n_hA  = n_y0 + (long)B * H;
    const long n_hX  = n_hA + 2L * BT * JQ * 1024;   // both parities (ushort)
    const long total = n_hX + 1024;                  // barrier words
    for (long idx = (long)blockIdx.x * 256 + threadIdx.x; idx < total;
         idx += (long)gridDim.x * 256) {
        if (idx < n_out)       out[idx] = bl[idx & (ID - 1)];
        else if (idx < n_y0)   y0[idx - n_out] = bl[(idx - n_out) & (ID - 1)];
        else if (idx < n_hA)   hA[idx - n_y0] = 0.f;
        else if (idx < n_hX)   hX[idx - n_hA] = 0;
        else                   bar[idx - n_hX] = 0u;
    }
}

// Swizzle [Wh | Wi] (fp32) into MFMA-native bf16 B-fragments (r3-proven).
__global__ __launch_bounds__(256) void prep_swizzle(const float* __restrict__ Wh,
                                                    const float* __restrict__ Wi,
                                                    ushort* __restrict__ Bs) {
    const int t = blockIdx.x * 256 + threadIdx.x;
    constexpr int TOT = 3 * 32 * NKT * 64;
    if (t >= TOT) return;
    const int l   = t & 63;
    int rest      = t >> 6;
    const int kt  = rest % NKT;  rest /= NKT;
    const int jt  = rest & 31;
    const int g   = rest >> 5;
    const int j  = jt * 16 + (l & 15);
    const int kb = kt * 32 + ((l >> 4) << 3);
    ushort v[8];
    if (kt < 16) {
        const float* src = Wh + (long)(g * H + j) * H + kb;
        #pragma unroll
        for (int i = 0; i < 8; ++i) v[i] = bfbits(src[i]);
    } else {
        const float* src = Wi + (long)(g * H + j) * ID + (kb - H);
        #pragma unroll
        for (int i = 0; i < 8; ++i) v[i] = bfbits(src[i]);
    }
    *(short8*)(Bs + (size_t)t * 8) = *(short8*)v;
}

// Swizzle Wl [ID,H] into bf16 B-fragments (r4-proven).
__global__ __launch_bounds__(256) void prep_wl(const float* __restrict__ Wl,
                                               ushort* __restrict__ Wsl) {
    const int t = blockIdx.x * 256 + threadIdx.x;
    if (t >= 4 * 16 * 64) return;
    const int l  = t & 63;
    const int kt = (t >> 6) & 15;
    const int ct = t >> 10;
    const int jy = ct * 16 + (l & 15);
    const int kc = kt * 32 + ((l >> 4) << 3);
    ushort v[8];
    #pragma unroll
    for (int i = 0; i < 8; ++i) v[i] = bfbits(Wl[(long)jy * H + kc + i]);
    *(short8*)(Wsl + (size_t)t * 8) = *(short8*)v;
}

// ---- A-fragment coherent load (parity-selected h tile set) ------------------
// Tile (p, btile, q) is 16x64 bf16 row-major at hX + ((p*BT+btile)*JQ+q)*1024.
// Fragment kt: lane reads tile q=kt>>1, 16B at row r16, col (kt&1)*32 + kq*8.
#define A_LOAD(dstarr, par)                                                     \
    _Pragma("unroll")                                                           \
    for (int kt = 0; kt < 16; ++kt) {                                           \
        const ushort* ap = hX + ((((size_t)(par) * BT + btile) * JQ)            \
                           + (kt >> 1)) * 1024 + r16 * 64 + (kt & 1) * 32 + c0; \
        asm volatile("global_load_dwordx4 %0, %1, off sc0 sc1"                  \
                     : "=v"(dstarr[kt]) : "v"(ap) : "memory");                  \
    }                                                                           \
    asm volatile("s_waitcnt vmcnt(0)" ::: "memory");                            \
    __builtin_amdgcn_sched_barrier(0);

// ---- THE persistent kernel --------------------------------------------------
// 256 blocks (1/CU) x 256 thr: btile = bk&31 (16 rows), jq = bk>>5 (64 cols).
// Wave w handles jt = jq*4+w (16 cols, all 3 gates). Sync group = 8 blocks/btile.
__global__ __launch_bounds__(256, 1) void gru_exchange(
    const float* __restrict__ x, const ushort* __restrict__ Bs,
    const ushort* __restrict__ Wsl, const float* __restrict__ bi,
    const float* __restrict__ bh, const float* __restrict__ bl,
    ushort* __restrict__ hX, uint* __restrict__ bar,
    float* __restrict__ out)
{
    __shared__ ushort wl_lds[4 * 16 * 64 * 8];  // 64 KB swizzled Wl
    __shared__ ushort lt[16][68];               // 2.2 KB transpose tile
    __shared__ ushort ysm[2][16][72];           // 4.6 KB y ping-pong

    const int tid = threadIdx.x, w = tid >> 6, l = tid & 63;
    const int r16 = l & 15, kq = l >> 4, c0 = kq * 8;
    const int bk = blockIdx.x;
    const int btile = bk & 31, jq = bk >> 5;
    const int jt = jq * 4 + w;
    const int j = jt * 16 + r16;
    uint* cnt = bar + btile * 32;

    // stage Wl fragments into LDS
    #pragma unroll
    for (int i = 0; i < 16; ++i) {
        const int idx = tid + i * 256;
        *(short8*)(wl_lds + (size_t)idx * 8) = *(const short8*)(Wsl + (size_t)idx * 8);
    }

    const float bir = bi[j] + bh[j];
    const float biz = bi[H + j] + bh[H + j];
    const float bin = bi[2 * H + j];
    const float bhn = bh[2 * H + j];
    const float blw = bl[w * 16 + r16];

    constexpr size_t GS = (size_t)32 * NKT * 512;  // ushorts per gate in Bs
    const ushort* bsw = Bs + (size_t)jt * NKT * 512 + ((size_t)l << 3);

    float hprev[4] = {0.f, 0.f, 0.f, 0.f};
    const float* xrow = x + (size_t)(btile * 16 + r16) * S * ID;
    float4v xa = *(const float4v*)(xrow + c0);
    float4v xb = *(const float4v*)(xrow + c0 + 4);
    float4v xc = *(const float4v*)(xrow + 32 + c0);
    float4v xd = *(const float4v*)(xrow + 36 + c0);
    __syncthreads();

    // epilogue + packed coherent store + group sync, shared by enc/dec
    auto finish_step = [&](float4v& ar, float4v& az, float4v& anh, float4v& anx,
                           int np, uint tgt) {
        #pragma unroll
        for (int c = 0; c < 4; ++c) {
            const float r = 1.f / (1.f + __expf(-(ar[c] + bir)));
            const float z = 1.f / (1.f + __expf(-(az[c] + biz)));
            const float e = __expf(2.f * (anx[c] + bin + r * (anh[c] + bhn)));
            const float n = 1.f - 2.f / (e + 1.f);
            const float h = (1.f - z) * n + z * hprev[c];
            hprev[c] = h;
            lt[kq * 4 + c][w * 16 + r16] = bfbits(h);   // transpose via LDS
        }
        __syncthreads();
        const int prow = tid >> 4, pc4 = (tid & 15) * 4;
        const u64t pv = *(const u64t*)&lt[prow][pc4];
        ushort* dp = hX + ((((size_t)np * BT + btile) * JQ) + jq) * 1024
                   + prow * 64 + pc4;
        asm volatile("global_store_dwordx2 %0, %1, off sc0 sc1"
                     :: "v"(dp), "v"(pv) : "memory");
        asm volatile("s_waitcnt vmcnt(0)" ::: "memory");
        __syncthreads();
        if (tid == 0) {
            __hip_atomic_fetch_add(cnt, 1u, __ATOMIC_RELAXED, __HIP_MEMORY_SCOPE_AGENT);
            while (__hip_atomic_load(cnt, __ATOMIC_RELAXED, __HIP_MEMORY_SCOPE_AGENT) < tgt) {}
        }
        __syncthreads();
    };

    short8 hv[16];

    // ===================== encoder =====================
    for (int t = 0; t < S; ++t) {
        const int p = t & 1;
        // B-fragments first: L2 stream overlaps A-latency + prior-step drain
        short8 bfr[NKT][3];
        #pragma unroll
        for (int kt = 0; kt < NKT; ++kt)
            #pragma unroll
            for (int g = 0; g < 3; ++g)
                bfr[kt][g] = *(const short8*)(bsw + (size_t)g * GS + (size_t)kt * 512);
        A_LOAD(hv, p);
        const short8 a16 = pack8(xa, xb), a17 = pack8(xc, xd);
        if (t + 1 < S) {   // prefetch next x (completes under MFMA/epilogue)
            const float* xr = xrow + (size_t)(t + 1) * ID;
            xa = *(const float4v*)(xr + c0);      xb = *(const float4v*)(xr + c0 + 4);
            xc = *(const float4v*)(xr + 32 + c0); xd = *(const float4v*)(xr + 36 + c0);
        }
        float4v ar{0.f,0.f,0.f,0.f}, az{0.f,0.f,0.f,0.f};
        float4v anh{0.f,0.f,0.f,0.f}, anx{0.f,0.f,0.f,0.f};
        #pragma unroll
        for (int kt = 0; kt < 16; ++kt) {
            ar  = __builtin_amdgcn_mfma_f32_16x16x32_bf16(hv[kt], bfr[kt][0], ar, 0, 0, 0);
            az  = __builtin_amdgcn_mfma_f32_16x16x32_bf16(hv[kt], bfr[kt][1], az, 0, 0, 0);
            anh = __builtin_amdgcn_mfma_f32_16x16x32_bf16(hv[kt], bfr[kt][2], anh, 0, 0, 0);
        }
        ar  = __builtin_amdgcn_mfma_f32_16x16x32_bf16(a16, bfr[16][0], ar, 0, 0, 0);
        az  = __builtin_amdgcn_mfma_f32_16x16x32_bf16(a16, bfr[16][1], az, 0, 0, 0);
        anx = __builtin_amdgcn_mfma_f32_16x16x32_bf16(a16, bfr[16][2], anx, 0, 0, 0);
        ar  = __builtin_amdgcn_mfma_f32_16x16x32_bf16(a17, bfr[17][0], ar, 0, 0, 0);
        az  = __builtin_amdgcn_mfma_f32_16x16x32_bf16(a17, bfr[17][1], az, 0, 0, 0);
        anx = __builtin_amdgcn_mfma_f32_16x16x32_bf16(a17, bfr[17][2], anx, 0, 0, 0);
        finish_step(ar, az, anh, anx, p ^ 1, 8u * (uint)(t + 1));
    }

    // ===================== y0 from h_n (parity 0) =====================
    {
        A_LOAD(hv, 0);
        float4v yac{0.f, 0.f, 0.f, 0.f};
        #pragma unroll
        for (int kt = 0; kt < 16; ++kt) {
            const short8 wb = *(const short8*)(wl_lds + ((size_t)(w * 16 + kt) * 64 + l) * 8);
            yac = __builtin_amdgcn_mfma_f32_16x16x32_bf16(hv[kt], wb, yac, 0, 0, 0);
        }
        #pragma unroll
        for (int c = 0; c < 4; ++c)
            ysm[0][kq * 4 + c][w * 16 + r16] = bfbits(yac[c] + blw);
        __syncthreads();
    }

    // ===================== decoder =====================
    // hv carries h(parity t&1) loaded by the previous compute_y / y0 block.
    for (int t = 0; t < T; ++t) {
        const int p = t & 1;
        short8 bfr[NKT][3];
        #pragma unroll
        for (int kt = 0; kt < NKT; ++kt)
            #pragma unroll
            for (int g = 0; g < 3; ++g)
                bfr[kt][g] = *(const short8*)(bsw + (size_t)g * GS + (size_t)kt * 512);
        const short8 a16 = *(const short8*)&ysm[p][r16][c0];
        const short8 a17 = *(const short8*)&ysm[p][r16][32 + c0];
        float4v ar{0.f,0.f,0.f,0.f}, az{0.f,0.f,0.f,0.f};
        float4v anh{0.f,0.f,0.f,0.f}, anx{0.f,0.f,0.f,0.f};
        #pragma unroll
        for (int kt = 0; kt < 16; ++kt) {
            ar  = __builtin_amdgcn_mfma_f32_16x16x32_bf16(hv[kt], bfr[kt][0], ar, 0, 0, 0);
            az  = __builtin_amdgcn_mfma_f32_16x16x32_bf16(hv[kt], bfr[kt][1], az, 0, 0, 0);
            anh = __builtin_amdgcn_mfma_f32_16x16x32_bf16(hv[kt], bfr[kt][2], anh, 0, 0, 0);
        }
        ar  = __builtin_amdgcn_mfma_f32_16x16x32_bf16(a16, bfr[16][0], ar, 0, 0, 0);
        az  = __builtin_amdgcn_mfma_f32_16x16x32_bf16(a16, bfr[16][1], az, 0, 0, 0);
        anx = __builtin_amdgcn_mfma_f32_16x16x32_bf16(a16, bfr[16][2], anx, 0, 0, 0);
        ar  = __builtin_amdgcn_mfma_f32_16x16x32_bf16(a17, bfr[17][0], ar, 0, 0, 0);
        az  = __builtin_amdgcn_mfma_f32_16x16x32_bf16(a17, bfr[17][1], az, 0, 0, 0);
        anx = __builtin_amdgcn_mfma_f32_16x16x32_bf16(a17, bfr[17][2], anx, 0, 0, 0);
        finish_step(ar, az, anh, anx, p ^ 1, 8u * (uint)(S + t + 1));

        // y_{t+1} = h_{t+1} @ Wl.T + bl; reload hv (parity p^1) for next iter
        A_LOAD(hv, p ^ 1);
        float4v yac{0.f, 0.f, 0.f, 0.f};
        #pragma unroll
        for (int kt = 0; kt < 16; ++kt) {
            const short8 wb = *(const short8*)(wl_lds + ((size_t)(w * 16 + kt) * 64 + l) * 8);
            yac = __builtin_amdgcn_mfma_f32_16x16x32_bf16(hv[kt], wb, yac, 0, 0, 0);
        }
        #pragma unroll
        for (int c = 0; c < 4; ++c) {
            const float yv = yac[c] + blw;
            ysm[p ^ 1][kq * 4 + c][w * 16 + r16] = bfbits(yv);
            if (jq == 0)
                out[(size_t)(btile * 16 + kq * 4 + c) * T * ID + (size_t)t * ID
                    + w * 16 + r16] = yv;
        }
        __syncthreads();
    }
}

// ---- fallback path (r3 kernels, proven) -------------------------------------
__global__ __launch_bounds__(256) void gru_step_mfma(
    const float* __restrict__ xin, long xstride,
    const float* __restrict__ h_in, const ushort* __restrict__ Bs,
    const float* __restrict__ bi, const float* __restrict__ bh,
    float* __restrict__ h_out)
{
    const int tid = threadIdx.x;
    const int w = tid >> 6, l = tid & 63;
    const int btile = blockIdx.x & 31;
    const int jt    = ((blockIdx.x >> 5) << 2) + w;
    const int b0 = btile << 4;
    const int arow = b0 + (l & 15);
    const int kb = (l >> 4) << 3;
    float4v acc_r{0,0,0,0}, acc_z{0,0,0,0}, acc_nh{0,0,0,0}, acc_nx{0,0,0,0};
    constexpr size_t GSTEP = (size_t)32 * NKT * 512;
    const ushort* bsw = Bs + (size_t)jt * NKT * 512 + ((size_t)l << 3);
    const float* ah = h_in + (size_t)arow * H + kb;
    #pragma unroll
    for (int kt = 0; kt < 16; ++kt) {
        const short8 a  = cvt8(ah + kt * 32);
        const short8 br = *(const short8*)(bsw + ((size_t)kt << 9));
        const short8 bz = *(const short8*)(bsw + GSTEP + ((size_t)kt << 9));
        const short8 bn = *(const short8*)(bsw + 2 * GSTEP + ((size_t)kt << 9));
        acc_r  = __builtin_amdgcn_mfma_f32_16x16x32_bf16(a, br, acc_r, 0, 0, 0);
        acc_z  = __builtin_amdgcn_mfma_f32_16x16x32_bf16(a, bz, acc_z, 0, 0, 0);
        acc_nh = __builtin_amdgcn_mfma_f32_16x16x32_bf16(a, bn, acc_nh, 0, 0, 0);
    }
    const float* ax = xin + (size_t)arow * xstride + kb;
    #pragma unroll
    for (int kt = 16; kt < 18; ++kt) {
        const short8 a  = cvt8(ax + (kt - 16) * 32);
        const short8 br = *(const short8*)(bsw + ((size_t)kt << 9));
        const short8 bz = *(const short8*)(bsw + GSTEP + ((size_t)kt << 9));
        const short8 bn = *(const short8*)(bsw + 2 * GSTEP + ((size_t)kt << 9));
        acc_r  = __builtin_amdgcn_mfma_f32_16x16x32_bf16(a, br, acc_r, 0, 0, 0);
        acc_z  = __builtin_amdgcn_mfma_f32_16x16x32_bf16(a, bz, acc_z, 0, 0, 0);
        acc_nx = __builtin_amdgcn_mfma_f32_16x16x32_bf16(a, bn, acc_nx, 0, 0, 0);
    }
    const int j = (jt << 4) + (l & 15);
    const float bir = bi[j] + bh[j];
    const float biz = bi[H + j] + bh[H + j];
    const float bin = bi[2 * H + j];
    const float bhn = bh[2 * H + j];
    #pragma unroll
    for (int c = 0; c < 4; ++c) {
        const int b = b0 + ((l >> 4) << 2) + c;
        const float r = 1.f / (1.f + expf(-(acc_r[c] + bir)));
        const float z = 1.f / (1.f + expf(-(acc_z[c] + biz)));
        const float n = tanhf(acc_nx[c] + bin + r * (acc_nh[c] + bhn));
        h_out[(size_t)b * H + j] = (1.f - z) * n + z * h_in[(size_t)b * H + j];
    }
}

__global__ __launch_bounds__(64) void linear_y(
    const float* __restrict__ h, const float* __restrict__ Wl,
    float* __restrict__ dst, int dst_stride)
{
    const int b = blockIdx.x >> 2;
    const int s = blockIdx.x & 3;
    const int i = threadIdx.x;
    const float4* h4 = (const float4*)(h  + (long)b * H + s * 128);
    const float4* w4 = (const float4*)(Wl + (long)i * H + s * 128);
    float acc = 0.f;
    #pragma unroll
    for (int k = 0; k < 32; ++k) {
        const float4 a = h4[k];
        const float4 w = w4[k];
        acc += a.x * w.x + a.y * w.y + a.z * w.z + a.w * w.w;
    }
    atomicAdd(&dst[(long)b * dst_stride + i], acc);
}

extern "C" void kernel_launch(void* const* d_in, const int* in_sizes, int n_in,
                              void* d_out, int out_size, void* d_ws, size_t ws_size,
                              hipStream_t stream) {
    const float* x  = (const float*)d_in[0];
    const float* Wi = (const float*)d_in[1];
    const float* Wh = (const float*)d_in[2];
    const float* bi = (const float*)d_in[3];
    const float* bh = (const float*)d_in[4];
    const float* Wl = (const float*)d_in[5];
    const float* bl = (const float*)d_in[6];
    float* out = (float*)d_out;

    // workspace carve
    uint*   bar = (uint*)d_ws;                               // 4 KB
    ushort* hX  = (ushort*)((char*)d_ws + 4096);             // 1 MB (2x32x8x1024)
    ushort* Bs  = hX + (size_t)2 * BT * JQ * 1024;           // 1.73 MB
    ushort* Wsl = Bs + (size_t)3 * 32 * NKT * 512;           // 64 KB
    float*  hA  = (float*)(Wsl + (size_t)4 * 16 * 512);      // 1 MB (fallback)
    float*  hB  = hA + (size_t)B * H;                        // 1 MB (fallback)
    float*  y0  = hB + (size_t)B * H;                        // 128 KB (fallback)

    init_kernel<<<2048, 256, 0, stream>>>(out, y0, hA, hX, bar, bl);
    prep_swizzle<<<(3 * 32 * NKT * 64 + 255) / 256, 256, 0, stream>>>(Wh, Wi, Bs);
    prep_wl<<<(4 * 16 * 64 + 255) / 256, 256, 0, stream>>>(Wl, Wsl);

    // ---- preferred: single persistent cooperative kernel ----
    {
        const float* xa = x; const ushort* Bsa = Bs; const ushort* Wsla = Wsl;
        const float* bia = bi; const float* bha = bh; const float* bla = bl;
        ushort* hXa = hX; uint* bara = bar; float* outa = out;
        void* args[] = { &xa, &Bsa, &Wsla, &bia, &bha, &bla, &hXa, &bara, &outa };
        hipError_t e = hipLaunchCooperativeKernel((const void*)gru_exchange,
                                                  dim3(256), dim3(256), args, 0, stream);
        if (e == hipSuccess) return;
    }

    // ---- fallback: r3 per-step path ----
    const float* hin = hA; float* hout = hB;
    for (int t = 0; t < S; ++t) {
        gru_step_mfma<<<256, 256, 0, stream>>>(x + (long)t * ID, (long)S * ID,
                                               hin, Bs, bi, bh, hout);
        const float* tmp = hout; hout = (float*)hin; hin = tmp;
    }
    linear_y<<<B * 4, 64, 0, stream>>>(hin, Wl, y0, ID);
    const float* inp = y0; long instride = ID;
    for (int t = 0; t < T; ++t) {
        gru_step_mfma<<<256, 256, 0, stream>>>(inp, instride, hin, Bs, bi, bh, hout);
        const float* tmp = hout; hout = (float*)hin; hin = tmp;
        linear_y<<<B * 4, 64, 0, stream>>>(hin, Wl, out + (long)t * ID, T * ID);
        inp = out + (long)t * ID; instride = T * ID;
    }
}